// Round 1
// baseline (2664.059 us; speedup 1.0000x reference)
//
#include <hip/hip_runtime.h>
#include <hip/hip_bf16.h>
#include <math.h>

// ---------------------------------------------------------------------------
// GCN-VAE encoder, fp32 reference-accurate implementation.
// Pipeline per launch:
//   1. CSR build over destination nodes (col) including self-loops, with
//      symmetric-normalized edge weights norm = dinv[row]*dinv[col].
//   2. 5x (GEMM m = h@W  ->  CSR gather-aggregate + bias (+relu)).
//   3. amvo = mu + eps*exp(0.5*logvar)
//   4. segment_max over sorted batch -> x2 ; fc1(relu) ; fc2.
// ---------------------------------------------------------------------------

#define THREADS 256

__global__ void k_count(const int* __restrict__ col, int* __restrict__ counts, int E) {
    int e = blockIdx.x * blockDim.x + threadIdx.x;
    if (e < E) atomicAdd(&counts[col[e]], 1);
}

__global__ void k_dinv(const int* __restrict__ counts, float* __restrict__ dinv, int N) {
    int i = blockIdx.x * blockDim.x + threadIdx.x;
    if (i < N) dinv[i] = rsqrtf((float)(counts[i] + 1));   // +1 self loop
}

// Exclusive scan of (counts[i]+1) over N elements, single block of 1024.
__global__ __launch_bounds__(1024) void k_scan(const int* __restrict__ counts,
                                               int* __restrict__ offsets, int N) {
    __shared__ int ssum[1024];
    int tid = threadIdx.x;
    int chunk = (N + 1023) / 1024;
    int begin = tid * chunk;
    int end = begin + chunk; if (end > N) end = N;
    int s = 0;
    for (int i = begin; i < end; ++i) s += counts[i] + 1;
    ssum[tid] = s;
    __syncthreads();
    // Hillis-Steele inclusive scan
    for (int off = 1; off < 1024; off <<= 1) {
        int v = 0;
        if (tid >= off) v = ssum[tid - off];
        __syncthreads();
        if (tid >= off) ssum[tid] += v;
        __syncthreads();
    }
    int prefix = (tid == 0) ? 0 : ssum[tid - 1];
    for (int i = begin; i < end; ++i) {
        offsets[i] = prefix;
        prefix += counts[i] + 1;
    }
    if (end == N && begin < N) offsets[N] = prefix;
}

__global__ void k_init_cursor(const int* __restrict__ offsets, int* __restrict__ cursor, int N) {
    int i = blockIdx.x * blockDim.x + threadIdx.x;
    if (i < N) cursor[i] = offsets[i];
}

__global__ void k_scatter(const int* __restrict__ row, const int* __restrict__ col,
                          const float* __restrict__ dinv, int* __restrict__ cursor,
                          int* __restrict__ csr_row, float* __restrict__ csr_norm,
                          int E, int N) {
    int e = blockIdx.x * blockDim.x + threadIdx.x;
    if (e < E) {
        int r = row[e], c = col[e];
        int slot = atomicAdd(&cursor[c], 1);
        csr_row[slot] = r;
        csr_norm[slot] = dinv[r] * dinv[c];
    } else if (e < E + N) {
        int i = e - E;
        int slot = atomicAdd(&cursor[i], 1);
        csr_row[slot] = i;
        float d = dinv[i];
        csr_norm[slot] = d * d;
    }
}

// C[M,Nc] = A[M,K] @ W[K,Nc]  (+bias) (+relu). Nc % 64 == 0, K % 16 == 0.
// 64x64 tile, 256 threads, 4x4 microtile per thread.
__global__ __launch_bounds__(256) void k_gemm(const float* __restrict__ A,
                                              const float* __restrict__ W,
                                              const float* __restrict__ bias,
                                              float* __restrict__ C,
                                              int M, int K, int Nc, int dorelu) {
    __shared__ float sA[16][65];
    __shared__ float sB[16][65];
    int tx = threadIdx.x & 15;        // col group
    int ty = threadIdx.x >> 4;        // row group
    int bm = blockIdx.x * 64;
    int bn = blockIdx.y * 64;
    float acc[4][4] = {{0.f}};
    for (int k0 = 0; k0 < K; k0 += 16) {
        for (int l = threadIdx.x; l < 64 * 16; l += 256) {
            int m = l >> 4, kk = l & 15;
            int gm = bm + m;
            sA[kk][m] = (gm < M) ? A[(size_t)gm * K + k0 + kk] : 0.f;
        }
        for (int l = threadIdx.x; l < 16 * 64; l += 256) {
            int kk = l >> 6, n = l & 63;
            sB[kk][n] = W[(size_t)(k0 + kk) * Nc + bn + n];
        }
        __syncthreads();
        #pragma unroll
        for (int kk = 0; kk < 16; ++kk) {
            float a[4], b[4];
            #pragma unroll
            for (int i = 0; i < 4; ++i) a[i] = sA[kk][ty * 4 + i];
            #pragma unroll
            for (int j = 0; j < 4; ++j) b[j] = sB[kk][tx * 4 + j];
            #pragma unroll
            for (int i = 0; i < 4; ++i)
                #pragma unroll
                for (int j = 0; j < 4; ++j) acc[i][j] += a[i] * b[j];
        }
        __syncthreads();
    }
    #pragma unroll
    for (int i = 0; i < 4; ++i) {
        int gm = bm + ty * 4 + i;
        if (gm >= M) continue;
        #pragma unroll
        for (int j = 0; j < 4; ++j) {
            int gn = bn + tx * 4 + j;
            float v = acc[i][j];
            if (bias) v += bias[gn];
            if (dorelu) v = fmaxf(v, 0.f);
            C[(size_t)gm * Nc + gn] = v;
        }
    }
}

// out[node, c] = bias[c] + sum_slots norm * m[row, c]  (+relu)
__global__ void k_agg(const float* __restrict__ m, const int* __restrict__ offsets,
                      const int* __restrict__ csr_row, const float* __restrict__ csr_norm,
                      const float* __restrict__ bias, float* __restrict__ out,
                      int F, int dorelu) {
    int node = blockIdx.x;
    int off0 = offsets[node], off1 = offsets[node + 1];
    for (int c = threadIdx.x; c < F; c += blockDim.x) {
        float s = 0.f;
        for (int sl = off0; sl < off1; ++sl) {
            int r = csr_row[sl];
            s += csr_norm[sl] * m[(size_t)r * F + c];
        }
        s += bias[c];
        if (dorelu) s = fmaxf(s, 0.f);
        out[(size_t)node * F + c] = s;
    }
}

__global__ void k_amvo(const float* __restrict__ mu, const float* __restrict__ lv,
                       const float* __restrict__ eps, float* __restrict__ out, size_t n) {
    size_t i = (size_t)blockIdx.x * blockDim.x + threadIdx.x;
    if (i < n) out[i] = mu[i] + eps[i] * expf(0.5f * lv[i]);
}

__global__ void k_gstart(const int* __restrict__ batch, int* __restrict__ gstart, int Nn, int B) {
    int b = blockIdx.x * blockDim.x + threadIdx.x;
    if (b > B) return;
    int lo = 0, hi = Nn;
    while (lo < hi) {
        int mid = (lo + hi) >> 1;
        if (batch[mid] < b) lo = mid + 1; else hi = mid;
    }
    gstart[b] = lo;
}

__global__ void k_pool_max(const float* __restrict__ h, const int* __restrict__ gstart,
                           float* __restrict__ x2, int F) {
    int b = blockIdx.x;
    int s = gstart[b], e = gstart[b + 1];
    for (int c = threadIdx.x; c < F; c += blockDim.x) {
        float mv = -INFINITY;
        for (int i = s; i < e; ++i) mv = fmaxf(mv, h[(size_t)i * F + c]);
        x2[(size_t)b * F + c] = mv;
    }
}

static inline int ceil_div(int a, int b) { return (a + b - 1) / b; }

extern "C" void kernel_launch(void* const* d_in, const int* in_sizes, int n_in,
                              void* d_out, int out_size, void* d_ws, size_t ws_size,
                              hipStream_t stream) {
    const int F0 = 64;
    const int N = in_sizes[0] / F0;            // 100000
    const int E = in_sizes[1] / 2;             // 400000
    const int F4 = 4 * F0;                     // 256
    const int B = (out_size - 3 * N * F4) / 128;  // 512
    const int M = E + N;

    const float* x        = (const float*)d_in[0];
    const int*   ei       = (const int*)d_in[1];
    const int*   batch    = (const int*)d_in[2];
    const float* eps      = (const float*)d_in[3];
    const float* W1  = (const float*)d_in[4];  const float* b1  = (const float*)d_in[5];
    const float* W2  = (const float*)d_in[6];  const float* b2  = (const float*)d_in[7];
    const float* W3  = (const float*)d_in[8];  const float* b3  = (const float*)d_in[9];
    const float* Wmu = (const float*)d_in[10]; const float* bmu = (const float*)d_in[11];
    const float* Wlv = (const float*)d_in[12]; const float* blv = (const float*)d_in[13];
    const float* fc1w = (const float*)d_in[14]; const float* fc1b = (const float*)d_in[15];
    const float* fc2w = (const float*)d_in[16]; const float* fc2b = (const float*)d_in[17];

    const int* e_row = ei;          // edge_index[0]
    const int* e_col = ei + E;      // edge_index[1]

    float* out   = (float*)d_out;
    float* amvo  = out;
    float* mu    = out + (size_t)N * F4;
    float* lv    = out + 2 * (size_t)N * F4;
    float* pmvo  = out + 3 * (size_t)N * F4;

    // --- workspace carve ---
    char* w = (char*)d_ws;
    auto alloc = [&](size_t bytes) -> void* {
        void* p = (void*)w;
        w += (bytes + 255) & ~(size_t)255;
        return p;
    };
    float* dinv    = (float*)alloc((size_t)N * 4);
    int*   counts  = (int*)alloc((size_t)N * 4);       // later reused as cursor
    int*   offsets = (int*)alloc((size_t)(N + 1) * 4);
    int*   csr_row = (int*)alloc((size_t)M * 4);
    float* csr_nrm = (float*)alloc((size_t)M * 4);
    int*   gstart  = (int*)alloc((size_t)(B + 1) * 4);
    float* m_buf   = (float*)alloc((size_t)N * F4 * 4);
    float* hA      = (float*)alloc((size_t)N * F4 * 4);   // h1 then h3
    float* hB      = (float*)alloc((size_t)N * 3 * F0 * 4); // h2
    float* x2      = (float*)alloc((size_t)B * F4 * 4);
    float* hid     = (float*)alloc((size_t)B * 1024 * 4);
    (void)ws_size; (void)n_in;

    // --- 1. graph structure ---
    hipMemsetAsync(counts, 0, (size_t)N * 4, stream);
    k_count<<<ceil_div(E, THREADS), THREADS, 0, stream>>>(e_col, counts, E);
    k_dinv<<<ceil_div(N, THREADS), THREADS, 0, stream>>>(counts, dinv, N);
    k_scan<<<1, 1024, 0, stream>>>(counts, offsets, N);
    k_init_cursor<<<ceil_div(N, THREADS), THREADS, 0, stream>>>(offsets, counts, N);
    k_scatter<<<ceil_div(E + N, THREADS), THREADS, 0, stream>>>(
        e_row, e_col, dinv, counts, csr_row, csr_nrm, E, N);

    // --- 2. GCN stack ---
    // layer1: x[N,64] @ W1 -> m[N,128]; agg -> hA (relu)
    {
        dim3 g(ceil_div(N, 64), 128 / 64);
        k_gemm<<<g, 256, 0, stream>>>(x, W1, nullptr, m_buf, N, 64, 128, 0);
        k_agg<<<N, 128, 0, stream>>>(m_buf, offsets, csr_row, csr_nrm, b1, hA, 128, 1);
    }
    // layer2: hA[N,128] @ W2 -> m[N,192]; agg -> hB (relu)
    {
        dim3 g(ceil_div(N, 64), 192 / 64);
        k_gemm<<<g, 256, 0, stream>>>(hA, W2, nullptr, m_buf, N, 128, 192, 0);
        k_agg<<<N, 192, 0, stream>>>(m_buf, offsets, csr_row, csr_nrm, b2, hB, 192, 1);
    }
    // layer3: hB[N,192] @ W3 -> m[N,256]; agg -> hA (relu)  [h3]
    {
        dim3 g(ceil_div(N, 64), 256 / 64);
        k_gemm<<<g, 256, 0, stream>>>(hB, W3, nullptr, m_buf, N, 192, 256, 0);
        k_agg<<<N, 256, 0, stream>>>(m_buf, offsets, csr_row, csr_nrm, b3, hA, 256, 1);
    }
    // mu: hA @ Wmu -> m; agg -> mu (no relu)
    {
        dim3 g(ceil_div(N, 64), 256 / 64);
        k_gemm<<<g, 256, 0, stream>>>(hA, Wmu, nullptr, m_buf, N, 256, 256, 0);
        k_agg<<<N, 256, 0, stream>>>(m_buf, offsets, csr_row, csr_nrm, bmu, mu, 256, 0);
    }
    // logvar: hA @ Wlv -> m; agg -> lv (no relu)
    {
        dim3 g(ceil_div(N, 64), 256 / 64);
        k_gemm<<<g, 256, 0, stream>>>(hA, Wlv, nullptr, m_buf, N, 256, 256, 0);
        k_agg<<<N, 256, 0, stream>>>(m_buf, offsets, csr_row, csr_nrm, blv, lv, 256, 0);
    }

    // --- 3. reparameterize ---
    {
        size_t n = (size_t)N * F4;
        k_amvo<<<(int)((n + THREADS - 1) / THREADS), THREADS, 0, stream>>>(mu, lv, eps, amvo, n);
    }

    // --- 4. pool + MLP ---
    k_gstart<<<ceil_div(B + 1, THREADS), THREADS, 0, stream>>>(batch, gstart, N, B);
    k_pool_max<<<B, 256, 0, stream>>>(hA, gstart, x2, F4);
    {
        dim3 g(ceil_div(B, 64), 1024 / 64);
        k_gemm<<<g, 256, 0, stream>>>(x2, fc1w, fc1b, hid, B, 256, 1024, 1);
    }
    {
        dim3 g(ceil_div(B, 64), 128 / 64);
        k_gemm<<<g, 256, 0, stream>>>(hid, fc2w, fc2b, pmvo, B, 1024, 128, 0);
    }
}

// Round 2
// 1357.781 us; speedup vs baseline: 1.9621x; 1.9621x over previous
//
#include <hip/hip_runtime.h>
#include <hip/hip_bf16.h>
#include <math.h>

// ---------------------------------------------------------------------------
// GCN-VAE encoder, round 2: bf16 MFMA GEMMs + aggregate-before-transform.
//   agg(norm * (h@W)) == (agg norm h) @ W   (aggregation is linear)
//   -> 4 gathers instead of 5 (mu/lv share agg(h3)), narrower channels.
// Pipeline:
//   1. CSR build (dest-ordered, self-loops, symmetric norm).
//   2. cast x->bf16; cast+transpose weights->bf16 (per launch).
//   3. g1=agg(x); h1=relu(g1@W1+b1); g2=agg(h1); h2=relu(g2@W2+b2);
//      g3=agg(h2); h3=relu(g3@W3+b3); g4=agg(h3);
//      mu=g4@Wmu+bmu; lv=g4@Wlv+blv   (fp32 out, straight to d_out)
//   4. amvo = mu + eps*exp(0.5*lv)
//   5. x2 = segmax(h3); pmvo = relu(x2@fc1+b)@fc2+b  (fp32 GEMM, tiny)
// ---------------------------------------------------------------------------

#define THREADS 256

typedef short s8v __attribute__((ext_vector_type(8)));   // 8 bf16 = 4 VGPR
typedef float f4v __attribute__((ext_vector_type(4)));   // MFMA accum

__device__ inline float bf_lo(unsigned int u) {
    union { unsigned int i; float f; } c; c.i = u << 16; return c.f;
}
__device__ inline float bf_hi(unsigned int u) {
    union { unsigned int i; float f; } c; c.i = u & 0xffff0000u; return c.f;
}
__device__ inline unsigned short f2bf(float f) {
    __hip_bfloat16 h = __float2bfloat16(f);
    return *reinterpret_cast<unsigned short*>(&h);
}
__device__ inline float bf2f(unsigned short u) {
    union { unsigned int i; float f; } c; c.i = ((unsigned int)u) << 16; return c.f;
}

// ------------------------- graph structure ---------------------------------

__global__ void k_count(const int* __restrict__ col, int* __restrict__ counts, int E) {
    int e = blockIdx.x * blockDim.x + threadIdx.x;
    if (e < E) atomicAdd(&counts[col[e]], 1);
}

__global__ void k_dinv(const int* __restrict__ counts, float* __restrict__ dinv, int N) {
    int i = blockIdx.x * blockDim.x + threadIdx.x;
    if (i < N) dinv[i] = rsqrtf((float)(counts[i] + 1));   // +1 self loop
}

__global__ __launch_bounds__(1024) void k_scan(const int* __restrict__ counts,
                                               int* __restrict__ offsets, int N) {
    __shared__ int ssum[1024];
    int tid = threadIdx.x;
    int chunk = (N + 1023) / 1024;
    int begin = tid * chunk;
    int end = begin + chunk; if (end > N) end = N;
    int s = 0;
    for (int i = begin; i < end; ++i) s += counts[i] + 1;
    ssum[tid] = s;
    __syncthreads();
    for (int off = 1; off < 1024; off <<= 1) {
        int v = 0;
        if (tid >= off) v = ssum[tid - off];
        __syncthreads();
        if (tid >= off) ssum[tid] += v;
        __syncthreads();
    }
    int prefix = (tid == 0) ? 0 : ssum[tid - 1];
    for (int i = begin; i < end; ++i) {
        offsets[i] = prefix;
        prefix += counts[i] + 1;
    }
    if (end == N && begin < N) offsets[N] = prefix;
}

__global__ void k_init_cursor(const int* __restrict__ offsets, int* __restrict__ cursor, int N) {
    int i = blockIdx.x * blockDim.x + threadIdx.x;
    if (i < N) cursor[i] = offsets[i];
}

__global__ void k_scatter(const int* __restrict__ row, const int* __restrict__ col,
                          const float* __restrict__ dinv, int* __restrict__ cursor,
                          int* __restrict__ csr_row, float* __restrict__ csr_norm,
                          int E, int N) {
    int e = blockIdx.x * blockDim.x + threadIdx.x;
    if (e < E) {
        int r = row[e], c = col[e];
        int slot = atomicAdd(&cursor[c], 1);
        csr_row[slot] = r;
        csr_norm[slot] = dinv[r] * dinv[c];
    } else if (e < E + N) {
        int i = e - E;
        int slot = atomicAdd(&cursor[i], 1);
        csr_row[slot] = i;
        float d = dinv[i];
        csr_norm[slot] = d * d;
    }
}

// ------------------------- casts / weight prep -----------------------------

__global__ void k_cast_bf16(const float* __restrict__ src, unsigned short* __restrict__ dst, int n) {
    int i = blockIdx.x * blockDim.x + threadIdx.x;
    if (i < n) dst[i] = f2bf(src[i]);
}

// W [K,Nc] fp32 -> WT [Nc,K] bf16
__global__ void k_prep_w(const float* __restrict__ W, unsigned short* __restrict__ WT,
                         int K, int Nc) {
    int id = blockIdx.x * blockDim.x + threadIdx.x;
    if (id < K * Nc) {
        int k = id / Nc, n = id % Nc;
        WT[(size_t)n * K + k] = f2bf(W[id]);
    }
}

// ------------------------- aggregation (gather, bf16 in/out) ---------------
// block: (F/8, nodes_per_block). Each thread owns 8 channels of one node.
__global__ void k_agg(const unsigned short* __restrict__ h,
                      const int* __restrict__ offsets,
                      const int* __restrict__ csr_row,
                      const float* __restrict__ csr_nrm,
                      unsigned short* __restrict__ g, int N, int F) {
    int node = blockIdx.x * blockDim.y + threadIdx.y;
    if (node >= N) return;
    int c8 = threadIdx.x * 8;
    int off0 = offsets[node], off1 = offsets[node + 1];
    float a0=0.f,a1=0.f,a2=0.f,a3=0.f,a4=0.f,a5=0.f,a6=0.f,a7=0.f;
    for (int sl = off0; sl < off1; ++sl) {
        int r = csr_row[sl];
        float w = csr_nrm[sl];
        uint4 v = *(const uint4*)(h + (size_t)r * F + c8);
        a0 += w * bf_lo(v.x); a1 += w * bf_hi(v.x);
        a2 += w * bf_lo(v.y); a3 += w * bf_hi(v.y);
        a4 += w * bf_lo(v.z); a5 += w * bf_hi(v.z);
        a6 += w * bf_lo(v.w); a7 += w * bf_hi(v.w);
    }
    uint4 o;
    o.x = (unsigned)f2bf(a0) | ((unsigned)f2bf(a1) << 16);
    o.y = (unsigned)f2bf(a2) | ((unsigned)f2bf(a3) << 16);
    o.z = (unsigned)f2bf(a4) | ((unsigned)f2bf(a5) << 16);
    o.w = (unsigned)f2bf(a6) | ((unsigned)f2bf(a7) << 16);
    *(uint4*)(g + (size_t)node * F + c8) = o;
}

// ------------------------- bf16 MFMA GEMM ----------------------------------
// C[M,Nc] = A[M,K](bf16) @ W (given as WT[Nc,K] bf16), +bias, opt relu.
// Out fp32 or bf16. BM=128, BN=64, BK=64, 256 threads (4 waves).
// Wave w: rows [w*32, w*32+32), all 64 cols -> 2x4 mfma tiles of 16x16.
#define GBM 128
#define GBN 64
#define GBK 64
#define LDP 72   // padded LDS row stride (shorts): +8 -> 4-bank shift/row

__global__ __launch_bounds__(256) void k_gemm_mfma(
    const unsigned short* __restrict__ A,
    const unsigned short* __restrict__ WT,
    const float* __restrict__ bias,
    void* __restrict__ Cout, int M, int K, int Nc,
    int dorelu, int out_bf16) {
    __shared__ unsigned short sA[GBM * LDP];
    __shared__ unsigned short sB[GBN * LDP];
    const int tid = threadIdx.x;
    const int wave = tid >> 6;
    const int lane = tid & 63;
    const int bm = blockIdx.x * GBM;
    const int bn = blockIdx.y * GBN;

    f4v acc[2][4];
    #pragma unroll
    for (int i = 0; i < 2; ++i)
        #pragma unroll
        for (int j = 0; j < 4; ++j) acc[i][j] = (f4v){0.f, 0.f, 0.f, 0.f};

    const int lrow = tid >> 3;          // 0..31
    const int lk = (tid & 7) * 8;       // 0,8,...,56
    const int fr = lane & 15;
    const int fk = (lane >> 4) * 8;

    for (int k0 = 0; k0 < K; k0 += GBK) {
        #pragma unroll
        for (int p = 0; p < 4; ++p) {
            int r = lrow + p * 32;
            int gm = bm + r;
            uint4 v = make_uint4(0u, 0u, 0u, 0u);
            if (gm < M) v = *(const uint4*)(A + (size_t)gm * K + k0 + lk);
            *(uint4*)(&sA[r * LDP + lk]) = v;
        }
        #pragma unroll
        for (int p = 0; p < 2; ++p) {
            int n = lrow + p * 32;
            uint4 v = *(const uint4*)(WT + (size_t)(bn + n) * K + k0 + lk);
            *(uint4*)(&sB[n * LDP + lk]) = v;
        }
        __syncthreads();
        #pragma unroll
        for (int ks = 0; ks < 2; ++ks) {
            s8v a0 = *(const s8v*)(&sA[(wave * 32 + fr) * LDP + ks * 32 + fk]);
            s8v a1 = *(const s8v*)(&sA[(wave * 32 + 16 + fr) * LDP + ks * 32 + fk]);
            #pragma unroll
            for (int nt = 0; nt < 4; ++nt) {
                s8v b = *(const s8v*)(&sB[(nt * 16 + fr) * LDP + ks * 32 + fk]);
                acc[0][nt] = __builtin_amdgcn_mfma_f32_16x16x32_bf16(a0, b, acc[0][nt], 0, 0, 0);
                acc[1][nt] = __builtin_amdgcn_mfma_f32_16x16x32_bf16(a1, b, acc[1][nt], 0, 0, 0);
            }
        }
        __syncthreads();
    }

    const int col_l = lane & 15;
    const int row_q = (lane >> 4) * 4;
    #pragma unroll
    for (int mt = 0; mt < 2; ++mt) {
        #pragma unroll
        for (int nt = 0; nt < 4; ++nt) {
            #pragma unroll
            for (int i = 0; i < 4; ++i) {
                int row = bm + wave * 32 + mt * 16 + row_q + i;
                int col = bn + nt * 16 + col_l;
                if (row < M) {
                    float v = acc[mt][nt][i] + bias[col];
                    if (dorelu) v = fmaxf(v, 0.f);
                    if (out_bf16)
                        ((unsigned short*)Cout)[(size_t)row * Nc + col] = f2bf(v);
                    else
                        ((float*)Cout)[(size_t)row * Nc + col] = v;
                }
            }
        }
    }
}

// ------------------------- fp32 GEMM (small FC layers) ---------------------
__global__ __launch_bounds__(256) void k_gemm(const float* __restrict__ A,
                                              const float* __restrict__ W,
                                              const float* __restrict__ bias,
                                              float* __restrict__ C,
                                              int M, int K, int Nc, int dorelu) {
    __shared__ float sA[16][65];
    __shared__ float sB[16][65];
    int tx = threadIdx.x & 15;
    int ty = threadIdx.x >> 4;
    int bm = blockIdx.x * 64;
    int bn = blockIdx.y * 64;
    float acc[4][4] = {{0.f}};
    for (int k0 = 0; k0 < K; k0 += 16) {
        for (int l = threadIdx.x; l < 64 * 16; l += 256) {
            int m = l >> 4, kk = l & 15;
            int gm = bm + m;
            sA[kk][m] = (gm < M) ? A[(size_t)gm * K + k0 + kk] : 0.f;
        }
        for (int l = threadIdx.x; l < 16 * 64; l += 256) {
            int kk = l >> 6, n = l & 63;
            sB[kk][n] = W[(size_t)(k0 + kk) * Nc + bn + n];
        }
        __syncthreads();
        #pragma unroll
        for (int kk = 0; kk < 16; ++kk) {
            float a[4], b[4];
            #pragma unroll
            for (int i = 0; i < 4; ++i) a[i] = sA[kk][ty * 4 + i];
            #pragma unroll
            for (int j = 0; j < 4; ++j) b[j] = sB[kk][tx * 4 + j];
            #pragma unroll
            for (int i = 0; i < 4; ++i)
                #pragma unroll
                for (int j = 0; j < 4; ++j) acc[i][j] += a[i] * b[j];
        }
        __syncthreads();
    }
    #pragma unroll
    for (int i = 0; i < 4; ++i) {
        int gm = bm + ty * 4 + i;
        if (gm >= M) continue;
        #pragma unroll
        for (int j = 0; j < 4; ++j) {
            int gn = bn + tx * 4 + j;
            float v = acc[i][j];
            if (bias) v += bias[gn];
            if (dorelu) v = fmaxf(v, 0.f);
            C[(size_t)gm * Nc + gn] = v;
        }
    }
}

// ------------------------- misc --------------------------------------------

__global__ void k_amvo(const float* __restrict__ mu, const float* __restrict__ lv,
                       const float* __restrict__ eps, float* __restrict__ out, size_t n) {
    size_t i = (size_t)blockIdx.x * blockDim.x + threadIdx.x;
    if (i < n) out[i] = mu[i] + eps[i] * expf(0.5f * lv[i]);
}

__global__ void k_gstart(const int* __restrict__ batch, int* __restrict__ gstart, int Nn, int B) {
    int b = blockIdx.x * blockDim.x + threadIdx.x;
    if (b > B) return;
    int lo = 0, hi = Nn;
    while (lo < hi) {
        int mid = (lo + hi) >> 1;
        if (batch[mid] < b) lo = mid + 1; else hi = mid;
    }
    gstart[b] = lo;
}

// max-pool over bf16 h3 -> fp32 x2
__global__ void k_pool_max(const unsigned short* __restrict__ h, const int* __restrict__ gstart,
                           float* __restrict__ x2, int F) {
    int b = blockIdx.x;
    int s = gstart[b], e = gstart[b + 1];
    for (int c = threadIdx.x; c < F; c += blockDim.x) {
        float mv = -INFINITY;
        for (int i = s; i < e; ++i) mv = fmaxf(mv, bf2f(h[(size_t)i * F + c]));
        x2[(size_t)b * F + c] = mv;
    }
}

static inline int ceil_div(int a, int b) { return (a + b - 1) / b; }

extern "C" void kernel_launch(void* const* d_in, const int* in_sizes, int n_in,
                              void* d_out, int out_size, void* d_ws, size_t ws_size,
                              hipStream_t stream) {
    const int F0 = 64;
    const int N = in_sizes[0] / F0;            // 100000
    const int E = in_sizes[1] / 2;             // 400000
    const int F4 = 4 * F0;                     // 256
    const int B = (out_size - 3 * N * F4) / 128;  // 512
    const int M = E + N;

    const float* x     = (const float*)d_in[0];
    const int*   ei    = (const int*)d_in[1];
    const int*   batch = (const int*)d_in[2];
    const float* eps   = (const float*)d_in[3];
    const float* W1  = (const float*)d_in[4];  const float* b1  = (const float*)d_in[5];
    const float* W2  = (const float*)d_in[6];  const float* b2  = (const float*)d_in[7];
    const float* W3  = (const float*)d_in[8];  const float* b3  = (const float*)d_in[9];
    const float* Wmu = (const float*)d_in[10]; const float* bmu = (const float*)d_in[11];
    const float* Wlv = (const float*)d_in[12]; const float* blv = (const float*)d_in[13];
    const float* fc1w = (const float*)d_in[14]; const float* fc1b = (const float*)d_in[15];
    const float* fc2w = (const float*)d_in[16]; const float* fc2b = (const float*)d_in[17];

    const int* e_row = ei;
    const int* e_col = ei + E;

    float* out  = (float*)d_out;
    float* amvo = out;
    float* mu   = out + (size_t)N * F4;
    float* lv   = out + 2 * (size_t)N * F4;
    float* pmvo = out + 3 * (size_t)N * F4;

    // --- workspace carve ---
    char* w = (char*)d_ws;
    auto alloc = [&](size_t bytes) -> void* {
        void* p = (void*)w;
        w += (bytes + 255) & ~(size_t)255;
        return p;
    };
    float* dinv    = (float*)alloc((size_t)N * 4);
    int*   counts  = (int*)alloc((size_t)N * 4);
    int*   offsets = (int*)alloc((size_t)(N + 1) * 4);
    int*   csr_row = (int*)alloc((size_t)M * 4);
    float* csr_nrm = (float*)alloc((size_t)M * 4);
    int*   gstart  = (int*)alloc((size_t)(B + 1) * 4);
    unsigned short* xb  = (unsigned short*)alloc((size_t)N * F0 * 2);
    unsigned short* h1  = (unsigned short*)alloc((size_t)N * 128 * 2);
    unsigned short* h2  = (unsigned short*)alloc((size_t)N * 192 * 2);
    unsigned short* h3  = (unsigned short*)alloc((size_t)N * 256 * 2);
    unsigned short* g   = (unsigned short*)alloc((size_t)N * 256 * 2);  // reused g1..g4
    unsigned short* wt1 = (unsigned short*)alloc((size_t)64 * 128 * 2);
    unsigned short* wt2 = (unsigned short*)alloc((size_t)128 * 192 * 2);
    unsigned short* wt3 = (unsigned short*)alloc((size_t)192 * 256 * 2);
    unsigned short* wtm = (unsigned short*)alloc((size_t)256 * 256 * 2);
    unsigned short* wtl = (unsigned short*)alloc((size_t)256 * 256 * 2);
    float* x2  = (float*)alloc((size_t)B * F4 * 4);
    float* hid = (float*)alloc((size_t)B * 1024 * 4);
    (void)ws_size; (void)n_in;

    // --- 1. graph structure ---
    hipMemsetAsync(counts, 0, (size_t)N * 4, stream);
    k_count<<<ceil_div(E, THREADS), THREADS, 0, stream>>>(e_col, counts, E);
    k_dinv<<<ceil_div(N, THREADS), THREADS, 0, stream>>>(counts, dinv, N);
    k_scan<<<1, 1024, 0, stream>>>(counts, offsets, N);
    k_init_cursor<<<ceil_div(N, THREADS), THREADS, 0, stream>>>(offsets, counts, N);
    k_scatter<<<ceil_div(E + N, THREADS), THREADS, 0, stream>>>(
        e_row, e_col, dinv, counts, csr_row, csr_nrm, E, N);

    // --- 2. casts + weight prep ---
    k_cast_bf16<<<ceil_div(N * F0, THREADS), THREADS, 0, stream>>>(x, xb, N * F0);
    k_prep_w<<<ceil_div(64 * 128, THREADS), THREADS, 0, stream>>>(W1, wt1, 64, 128);
    k_prep_w<<<ceil_div(128 * 192, THREADS), THREADS, 0, stream>>>(W2, wt2, 128, 192);
    k_prep_w<<<ceil_div(192 * 256, THREADS), THREADS, 0, stream>>>(W3, wt3, 192, 256);
    k_prep_w<<<ceil_div(256 * 256, THREADS), THREADS, 0, stream>>>(Wmu, wtm, 256, 256);
    k_prep_w<<<ceil_div(256 * 256, THREADS), THREADS, 0, stream>>>(Wlv, wtl, 256, 256);

    // --- 3. GCN stack: agg -> transform ---
    // g1 = agg(xb) [N,64]; h1 = relu(g1@W1+b1) [N,128]
    {
        dim3 blk(8, 32); // 64ch
        k_agg<<<ceil_div(N, 32), blk, 0, stream>>>(xb, offsets, csr_row, csr_nrm, g, N, 64);
        dim3 gg(ceil_div(N, GBM), 128 / GBN);
        k_gemm_mfma<<<gg, 256, 0, stream>>>(g, wt1, b1, h1, N, 64, 128, 1, 1);
    }
    // g2 = agg(h1) [N,128]; h2 = relu(g2@W2+b2) [N,192]
    {
        dim3 blk(16, 16);
        k_agg<<<ceil_div(N, 16), blk, 0, stream>>>(h1, offsets, csr_row, csr_nrm, g, N, 128);
        dim3 gg(ceil_div(N, GBM), 192 / GBN);
        k_gemm_mfma<<<gg, 256, 0, stream>>>(g, wt2, b2, h2, N, 128, 192, 1, 1);
    }
    // g3 = agg(h2) [N,192]; h3 = relu(g3@W3+b3) [N,256]
    {
        dim3 blk(24, 8);
        k_agg<<<ceil_div(N, 8), blk, 0, stream>>>(h2, offsets, csr_row, csr_nrm, g, N, 192);
        dim3 gg(ceil_div(N, GBM), 256 / GBN);
        k_gemm_mfma<<<gg, 256, 0, stream>>>(g, wt3, b3, h3, N, 192, 256, 1, 1);
    }
    // g4 = agg(h3) [N,256]; mu = g4@Wmu+bmu; lv = g4@Wlv+blv (fp32 out)
    {
        dim3 blk(32, 8);
        k_agg<<<ceil_div(N, 8), blk, 0, stream>>>(h3, offsets, csr_row, csr_nrm, g, N, 256);
        dim3 gg(ceil_div(N, GBM), 256 / GBN);
        k_gemm_mfma<<<gg, 256, 0, stream>>>(g, wtm, bmu, mu, N, 256, 256, 0, 0);
        k_gemm_mfma<<<gg, 256, 0, stream>>>(g, wtl, blv, lv, N, 256, 256, 0, 0);
    }

    // --- 4. reparameterize ---
    {
        size_t n = (size_t)N * F4;
        k_amvo<<<(int)((n + THREADS - 1) / THREADS), THREADS, 0, stream>>>(mu, lv, eps, amvo, n);
    }

    // --- 5. pool + MLP (fp32) ---
    k_gstart<<<ceil_div(B + 1, THREADS), THREADS, 0, stream>>>(batch, gstart, N, B);
    k_pool_max<<<B, 256, 0, stream>>>(h3, gstart, x2, F4);
    {
        dim3 gg(ceil_div(B, 64), 1024 / 64);
        k_gemm<<<gg, 256, 0, stream>>>(x2, fc1w, fc1b, hid, B, 256, 1024, 1);
    }
    {
        dim3 gg(ceil_div(B, 64), 128 / 64);
        k_gemm<<<gg, 256, 0, stream>>>(hid, fc2w, fc2b, pmvo, B, 1024, 128, 0);
    }
}